// Round 6
// baseline (671.691 us; speedup 1.0000x reference)
//
#include <hip/hip_runtime.h>

#define FD 64  // feature dim
#define SCAN_BLOCK 256
#define ELEMS_PER_THREAD 16
#define ELEMS_PER_BLOCK (SCAN_BLOCK * ELEMS_PER_THREAD)  // 4096
#define EDGE_CHUNK 16  // software-pipelined gathers per batch

static inline long long cdiv_ll(long long a, long long b) { return (a + b - 1) / b; }

// ---------------- fused CSR build (3 graphs concatenated) ----------------
// node-space layout: [il nodes (n1) | bi rows (B) | bl nodes (n2)]

__global__ void hist3_kernel(const int* __restrict__ r0, int nnz0,
                             const int* __restrict__ r1, int nnz1,
                             const int* __restrict__ r2, int nnz2,
                             int b1, int b2, int* __restrict__ counts) {
    int t = blockIdx.x * blockDim.x + threadIdx.x;
    if (t < nnz0) {
        atomicAdd(&counts[r0[t]], 1);
    } else if (t < nnz0 + nnz1) {
        atomicAdd(&counts[b1 + r1[t - nnz0]], 1);
    } else if (t < nnz0 + nnz1 + nnz2) {
        atomicAdd(&counts[b2 + r2[t - nnz0 - nnz1]], 1);
    }
}

// pass 1: per-block totals (4096 counts per block)
__global__ void block_sum_kernel(const int* __restrict__ counts, int* __restrict__ block_sums,
                                 int n) {
    int tid = threadIdx.x;
    int base = blockIdx.x * ELEMS_PER_BLOCK + tid * ELEMS_PER_THREAD;
    int s = 0;
#pragma unroll
    for (int i = 0; i < ELEMS_PER_THREAD; ++i) {
        int idx = base + i;
        if (idx < n) s += counts[idx];
    }
    __shared__ int red[SCAN_BLOCK];
    red[tid] = s;
    __syncthreads();
    for (int o = SCAN_BLOCK / 2; o > 0; o >>= 1) {
        if (tid < o) red[tid] += red[tid + o];
        __syncthreads();
    }
    if (tid == 0) block_sums[blockIdx.x] = red[0];
}

// pass 2: exclusive scan of block sums (nb <= 1024) in one block; writes total
__global__ void scan_sums_kernel(int* __restrict__ block_sums, int* __restrict__ total_out,
                                 int nb) {
    __shared__ int sh[1024];
    int tid = threadIdx.x;
    int v = (tid < nb) ? block_sums[tid] : 0;
    sh[tid] = v;
    __syncthreads();
    for (int o = 1; o < 1024; o <<= 1) {
        int t = 0;
        if (tid >= o) t = sh[tid - o];
        __syncthreads();
        sh[tid] += t;
        __syncthreads();
    }
    if (tid < nb) block_sums[tid] = sh[tid] - v;  // exclusive
    if (tid == nb - 1) *total_out = sh[tid];      // grand total -> row_ptr[n]
}

// per-node scale factors: il/bl nodes: 1/(sqrt(deg)+1e-8); bi rows: 1/(deg+1e-8)
__global__ void scales_kernel(const int* __restrict__ counts, float* __restrict__ scales,
                              int n1, int nbrows, int ntot) {
    int i = blockIdx.x * blockDim.x + threadIdx.x;
    if (i >= ntot) return;
    float c = (float)counts[i];
    bool is_bi = (i >= n1) && (i < n1 + nbrows);
    scales[i] = is_bi ? 1.0f / (c + 1e-8f) : 1.0f / (sqrtf(c) + 1e-8f);
}

// pass 3: per-block local exclusive scan + block offset -> row_ptr, cursor
// NOTE: cursor may alias counts (each index handled by exactly one thread:
// counts read before cursor write).
__global__ void scan_apply_kernel(const int* __restrict__ counts,
                                  const int* __restrict__ block_sums,
                                  int* __restrict__ row_ptr, int* __restrict__ cursor, int n) {
    int tid = threadIdx.x;
    int base = blockIdx.x * ELEMS_PER_BLOCK + tid * ELEMS_PER_THREAD;
    int local[ELEMS_PER_THREAD];
    int s = 0;
#pragma unroll
    for (int i = 0; i < ELEMS_PER_THREAD; ++i) {
        int idx = base + i;
        int c = (idx < n) ? counts[idx] : 0;
        local[i] = c;
        s += c;
    }
    __shared__ int sh[SCAN_BLOCK];
    sh[tid] = s;
    __syncthreads();
    for (int o = 1; o < SCAN_BLOCK; o <<= 1) {
        int t = 0;
        if (tid >= o) t = sh[tid - o];
        __syncthreads();
        sh[tid] += t;
        __syncthreads();
    }
    int off = block_sums[blockIdx.x] + sh[tid] - s;  // exclusive prefix for this thread
#pragma unroll
    for (int i = 0; i < ELEMS_PER_THREAD; ++i) {
        int idx = base + i;
        if (idx < n) {
            row_ptr[idx] = off;
            cursor[idx] = off;
            off += local[i];
        }
    }
}

// fused scatter: only column ids (values are recomputed from degrees)
__global__ void scatter3_kernel(const int* __restrict__ r0, const int* __restrict__ c0, int nnz0,
                                const int* __restrict__ r1, const int* __restrict__ c1, int nnz1,
                                const int* __restrict__ r2, const int* __restrict__ c2, int nnz2,
                                int b1, int b2, int* __restrict__ cursor,
                                int* __restrict__ scols) {
    int t = blockIdx.x * blockDim.x + threadIdx.x;
    int node, col;
    if (t < nnz0) {
        node = r0[t];             col = c0[t];
    } else if (t < nnz0 + nnz1) {
        int e = t - nnz0;         node = b1 + r1[e]; col = c1[e];
    } else if (t < nnz0 + nnz1 + nnz2) {
        int e = t - nnz0 - nnz1;  node = b2 + r2[e]; col = c2[e];
    } else {
        return;
    }
    int pos = atomicAdd(&cursor[node], 1);
    scols[pos] = col;
}

// ---------------- feature kernels ----------------

// xs[0:na+nb) = scales ⊙ concat(a,b);  acc_a = a; acc_b = b
__global__ void init_concat_kernel(const float* __restrict__ a, const float* __restrict__ b,
                                   int na, int nb, const float* __restrict__ scales,
                                   float* __restrict__ xs,
                                   float* __restrict__ acc_a, float* __restrict__ acc_b) {
    long long idx = (long long)blockIdx.x * blockDim.x + threadIdx.x;
    long long total = (long long)(na + nb) * FD;
    if (idx >= total) return;
    int row = (int)(idx >> 6);
    float v;
    if (row < na) {
        v = a[idx];
        acc_a[idx] = v;
    } else {
        long long j = idx - (long long)na * FD;
        v = b[j];
        acc_b[j] = v;
    }
    xs[idx] = scales[row] * v;
}

// one wave per row; edge loop software-pipelined (EDGE_CHUNK gathers in flight)
__device__ __forceinline__ float csr_row_gather(const int* __restrict__ row_ptr,
                                                const int* __restrict__ scols,
                                                const float* __restrict__ x,
                                                int wave, int lane) {
    int s = row_ptr[wave], e = row_ptr[wave + 1];
    float acc = 0.f;
    for (int base = s; base < e; base += EDGE_CHUNK) {
        int cbuf[EDGE_CHUNK];
#pragma unroll
        for (int k = 0; k < EDGE_CHUNK; ++k)
            cbuf[k] = scols[min(base + k, e - 1)];  // clamp tail (row non-empty here)
#pragma unroll
        for (int k = 0; k < EDGE_CHUNK; ++k) {
            float xv = x[(size_t)cbuf[k] * FD + lane];
            if (base + k < e) acc += xv;            // wave-uniform predicate
        }
    }
    return acc;
}

// f = scale * inv[row] * Σ xs[col];  if(write_xs) xs_out[row] = inv[row]*f;
// acc[row] += f / max(||f||, 1e-12)   (acc split across acc_a / acc_b at `split`)
__global__ void spmm_norm_kernel(const int* __restrict__ row_ptr,
                                 const int* __restrict__ scols,
                                 const float* __restrict__ inv,
                                 const float* __restrict__ x, float* __restrict__ xs_out,
                                 float* __restrict__ acc_a, float* __restrict__ acc_b,
                                 int split, int n, float scale, int write_xs) {
    int wave = (int)(((long long)blockIdx.x * blockDim.x + threadIdx.x) >> 6);
    if (wave >= n) return;
    int lane = threadIdx.x & 63;
    float iv = inv[wave];
    float f = scale * iv * csr_row_gather(row_ptr, scols, x, wave, lane);
    if (write_xs) xs_out[(size_t)wave * FD + lane] = iv * f;
    float ss = f * f;
#pragma unroll
    for (int o = 32; o >= 1; o >>= 1) ss += __shfl_xor(ss, o);
    float nrm = fmaxf(sqrtf(ss), 1e-12f);
    float add = f / nrm;
    if (wave < split)
        acc_a[(size_t)wave * FD + lane] += add;
    else
        acc_b[(size_t)(wave - split) * FD + lane] += add;
}

// y[row] = rowscale[row] * Σ x[col]  (bi aggregation)
__global__ void spmm_scale_kernel(const int* __restrict__ row_ptr,
                                  const int* __restrict__ scols,
                                  const float* __restrict__ rowscale,
                                  const float* __restrict__ x, float* __restrict__ y, int n) {
    int wave = (int)(((long long)blockIdx.x * blockDim.x + threadIdx.x) >> 6);
    if (wave >= n) return;
    int lane = threadIdx.x & 63;
    float acc = csr_row_gather(row_ptr, scols, x, wave, lane);
    y[(size_t)wave * FD + lane] = rowscale[wave] * acc;
}

extern "C" void kernel_launch(void* const* d_in, const int* in_sizes, int n_in,
                              void* d_out, int out_size, void* d_ws, size_t ws_size,
                              hipStream_t stream) {
    const float* users   = (const float*)d_in[0];
    const float* items   = (const float*)d_in[1];
    const float* bundles = (const float*)d_in[2];
    const int*   il_rows = (const int*)d_in[3];
    const int*   il_cols = (const int*)d_in[4];
    const int*   bl_rows = (const int*)d_in[6];
    const int*   bl_cols = (const int*)d_in[7];
    const int*   bi_rows = (const int*)d_in[9];
    const int*   bi_cols = (const int*)d_in[10];

    const int U = in_sizes[0] / FD;   // 50000
    const int I = in_sizes[1] / FD;   // 40000
    const int B = in_sizes[2] / FD;   // 20000
    const int nnz_il = in_sizes[3];   // 1,000,000
    const int nnz_bl = in_sizes[6];   //   600,000
    const int nnz_bi = in_sizes[9];   //   500,000
    const int n1 = U + I;             // 90000
    const int n2 = U + B;             // 70000
    const int ntot = n1 + B + n2;     // 180000 (il | bi | bl node spaces)
    const int nnz_tot = nnz_il + nnz_bi + nnz_bl;  // 2,100,000
    const int base_bi = n1, base_bl = n1 + B;

    float* out = (float*)d_out;
    // output layout: [il_users (U) | bl_users (U) | il_bundles (B) | bl_bundles (B)] x 64
    float* il_users_acc   = out;
    float* bl_users_acc   = out + (size_t)U * FD;
    float* il_bundles_out = out + (size_t)2 * U * FD;
    float* bl_bundles_acc = out + ((size_t)2 * U + B) * FD;

    // workspace layout
    float* ping       = (float*)d_ws;                       // n1 x 64
    float* pong       = ping + (size_t)n1 * FD;             // n1 x 64
    float* items_acc  = pong + (size_t)n1 * FD;             // I x 64
    int*   counts     = (int*)(items_acc + (size_t)I * FD); // ntot (later reused as cursor)
    int*   row_ptr    = counts + ntot;                      // ntot + 1
    float* scales     = (float*)(row_ptr + ntot + 1);       // ntot
    int*   block_sums = (int*)(scales + ntot);              // <= 1024
    int*   scols      = block_sums + 1024;                  // nnz_tot (absolute positions)
    int*   cursor     = counts;                             // overlay (counts dead after scales)

    const dim3 blk(256);
    const int nb = (int)cdiv_ll(ntot, ELEMS_PER_BLOCK);
    const int grid_n1 = (int)cdiv_ll((long long)n1 * FD, 256);
    const int grid_n2 = (int)cdiv_ll((long long)n2 * FD, 256);
    const float h = 0.5f, th = 1.0f / 3.0f;

    // ---------------- fused CSR build for all three graphs ----------------
    hipMemsetAsync(counts, 0, (size_t)ntot * sizeof(int), stream);
    hist3_kernel<<<(int)cdiv_ll(nnz_tot, 256), blk, 0, stream>>>(
        il_rows, nnz_il, bi_rows, nnz_bi, bl_rows, nnz_bl, base_bi, base_bl, counts);
    block_sum_kernel<<<nb, SCAN_BLOCK, 0, stream>>>(counts, block_sums, ntot);
    scan_sums_kernel<<<1, 1024, 0, stream>>>(block_sums, row_ptr + ntot, nb);
    scales_kernel<<<(int)cdiv_ll(ntot, 256), blk, 0, stream>>>(counts, scales, n1, B, ntot);
    scan_apply_kernel<<<nb, SCAN_BLOCK, 0, stream>>>(counts, block_sums, row_ptr, cursor, ntot);
    scatter3_kernel<<<(int)cdiv_ll(nnz_tot, 256), blk, 0, stream>>>(
        il_rows, il_cols, nnz_il, bi_rows, bi_cols, nnz_bi, bl_rows, bl_cols, nnz_bl,
        base_bi, base_bl, cursor, scols);

    // ---------------- item-level propagation (users + items, il graph) ------------
    init_concat_kernel<<<grid_n1, blk, 0, stream>>>(users, items, U, I, scales,
                                                    ping, il_users_acc, items_acc);
    spmm_norm_kernel<<<grid_n1, blk, 0, stream>>>(row_ptr, scols, scales, ping, pong,
                                                  il_users_acc, items_acc, U, n1, h, 1);
    spmm_norm_kernel<<<grid_n1, blk, 0, stream>>>(row_ptr, scols, scales, pong, ping,
                                                  il_users_acc, items_acc, U, n1, th, 0);

    // bundle aggregation: il_bundles = rowscale_bi * (BI @ il_items_acc)
    spmm_scale_kernel<<<(int)cdiv_ll((long long)B * FD, 256), blk, 0, stream>>>(
        row_ptr + base_bi, scols, scales + base_bi, items_acc, il_bundles_out, B);

    // ---------------- bundle-level propagation (users + bundles, bl graph) --------
    init_concat_kernel<<<grid_n2, blk, 0, stream>>>(users, bundles, U, B, scales + base_bl,
                                                    ping, bl_users_acc, bl_bundles_acc);
    spmm_norm_kernel<<<grid_n2, blk, 0, stream>>>(row_ptr + base_bl, scols, scales + base_bl,
                                                  ping, pong,
                                                  bl_users_acc, bl_bundles_acc, U, n2, h, 1);
    spmm_norm_kernel<<<grid_n2, blk, 0, stream>>>(row_ptr + base_bl, scols, scales + base_bl,
                                                  pong, ping,
                                                  bl_users_acc, bl_bundles_acc, U, n2, th, 0);
}

// Round 7
// 544.301 us; speedup vs baseline: 1.2340x; 1.2340x over previous
//
#include <hip/hip_runtime.h>

#define FD 64          // feature dim
#define EDGE_CHUNK 16  // software-pipelined gathers per batch
#define MAXB 256       // max buckets (ntot/1024 = 176 here)
#define BROWS 1024     // rows per bucket
#define PART_BLOCK 256
#define PART_VPT 16
#define PART_EPB (PART_BLOCK * PART_VPT)  // 4096 edges per partition block

static inline long long cdiv_ll(long long a, long long b) { return (a + b - 1) / b; }

// =================== fused CSR build via radix partition ===================
// node-space layout: [il nodes (n1) | bi rows (B) | bl nodes (n2)], bucket = node>>10

// K1: per-bucket edge histogram (LDS-reduced)
__global__ void bucket_hist_kernel(const int* __restrict__ r0, int nnz0,
                                   const int* __restrict__ r1, int nnz1,
                                   const int* __restrict__ r2, int nnz2,
                                   int b1, int b2, int nnz_tot, int nbuckets,
                                   int* __restrict__ bucket_count) {
    __shared__ int h[MAXB];
    for (int i = threadIdx.x; i < MAXB; i += blockDim.x) h[i] = 0;
    __syncthreads();
    int stride = gridDim.x * blockDim.x;
    for (int t = blockIdx.x * blockDim.x + threadIdx.x; t < nnz_tot; t += stride) {
        int node;
        if (t < nnz0) node = r0[t];
        else if (t < nnz0 + nnz1) node = b1 + r1[t - nnz0];
        else node = b2 + r2[t - nnz0 - nnz1];
        atomicAdd(&h[node >> 10], 1);
    }
    __syncthreads();
    for (int i = threadIdx.x; i < nbuckets; i += blockDim.x)
        if (h[i]) atomicAdd(&bucket_count[i], h[i]);
}

// K2: exclusive scan of bucket counts (nbuckets <= 256), one block of 256
__global__ void bucket_scan_kernel(const int* __restrict__ bucket_count,
                                   int* __restrict__ bucket_base,
                                   int* __restrict__ bucket_cursor, int nbuckets) {
    __shared__ int sh[MAXB];
    int tid = threadIdx.x;
    int v = (tid < nbuckets) ? bucket_count[tid] : 0;
    sh[tid] = v;
    __syncthreads();
    for (int o = 1; o < MAXB; o <<= 1) {
        int t = (tid >= o) ? sh[tid - o] : 0;
        __syncthreads();
        sh[tid] += t;
        __syncthreads();
    }
    int excl = sh[tid] - v;
    if (tid < nbuckets) { bucket_base[tid] = excl; bucket_cursor[tid] = excl; }
    if (tid == nbuckets - 1) bucket_base[nbuckets] = sh[tid];
}

// K3: partition edges into bucket-contiguous tmp, packed (local_row<<17 | col)
__global__ void partition_kernel(const int* __restrict__ r0, const int* __restrict__ c0, int nnz0,
                                 const int* __restrict__ r1, const int* __restrict__ c1, int nnz1,
                                 const int* __restrict__ r2, const int* __restrict__ c2, int nnz2,
                                 int b1, int b2, int nnz_tot, int nbuckets,
                                 int* __restrict__ bucket_cursor, unsigned int* __restrict__ tmp) {
    __shared__ int h[MAXB];
    __shared__ int base[MAXB];
    for (int i = threadIdx.x; i < MAXB; i += PART_BLOCK) h[i] = 0;
    __syncthreads();
    int blk_start = blockIdx.x * PART_EPB;
    int node[PART_VPT];
    int col[PART_VPT];
#pragma unroll
    for (int k = 0; k < PART_VPT; ++k) {
        int t = blk_start + k * PART_BLOCK + threadIdx.x;  // coalesced
        int nd = -1, cc = 0;
        if (t < nnz0) { nd = r0[t]; cc = c0[t]; }
        else if (t < nnz0 + nnz1) { int e = t - nnz0; nd = b1 + r1[e]; cc = c1[e]; }
        else if (t < nnz_tot)     { int e = t - nnz0 - nnz1; nd = b2 + r2[e]; cc = c2[e]; }
        node[k] = nd; col[k] = cc;
        if (nd >= 0) atomicAdd(&h[nd >> 10], 1);
    }
    __syncthreads();
    for (int i = threadIdx.x; i < nbuckets; i += PART_BLOCK) {
        int c = h[i];
        base[i] = c ? atomicAdd(&bucket_cursor[i], c) : 0;
        h[i] = 0;  // reuse as local write offset
    }
    __syncthreads();
#pragma unroll
    for (int k = 0; k < PART_VPT; ++k) {
        int nd = node[k];
        if (nd < 0) continue;
        int bkt = nd >> 10;
        int off = atomicAdd(&h[bkt], 1);
        tmp[base[bkt] + off] = ((unsigned)(nd & (BROWS - 1)) << 17) | (unsigned)col[k];
    }
}

// K4: one block per bucket — per-node counts (LDS), in-block scan -> row_ptr +
// scales, then locally-scattered scols via LDS cursors.
__global__ void finalize_kernel(const unsigned int* __restrict__ tmp,
                                const int* __restrict__ bucket_base,
                                int* __restrict__ row_ptr, float* __restrict__ scales,
                                int* __restrict__ scols,
                                int n1, int nbi, int ntot, int nbuckets) {
    __shared__ int cnt[BROWS];
    __shared__ int cur[BROWS];
    __shared__ int tsum[256];
    int b = blockIdx.x;
    int tid = threadIdx.x;
    int rstart = b << 10;
    int bstart = bucket_base[b], bend = bucket_base[b + 1];
    for (int i = tid; i < BROWS; i += 256) cnt[i] = 0;
    __syncthreads();
    for (int j = bstart + tid; j < bend; j += 256)
        atomicAdd(&cnt[tmp[j] >> 17], 1);
    __syncthreads();
    // exclusive scan of cnt[1024]: 4 per thread + Hillis-Steele over 256 partials
    int s0 = cnt[tid * 4], s1 = cnt[tid * 4 + 1], s2 = cnt[tid * 4 + 2], s3 = cnt[tid * 4 + 3];
    int ts = s0 + s1 + s2 + s3;
    tsum[tid] = ts;
    __syncthreads();
    for (int o = 1; o < 256; o <<= 1) {
        int t = (tid >= o) ? tsum[tid - o] : 0;
        __syncthreads();
        tsum[tid] += t;
        __syncthreads();
    }
    int p0 = bstart + tsum[tid] - ts;
    int p1 = p0 + s0, p2 = p1 + s1, p3 = p2 + s2;
    {
        int i0 = tid * 4;
        int pos[4] = {p0, p1, p2, p3};
        int cc[4] = {s0, s1, s2, s3};
#pragma unroll
        for (int q = 0; q < 4; ++q) {
            int i = i0 + q, r = rstart + i;
            if (r < ntot) {
                row_ptr[r] = pos[q];
                cur[i] = pos[q];
                float c = (float)cc[q];
                scales[r] = (r >= n1 && r < n1 + nbi) ? 1.0f / (c + 1e-8f)
                                                      : 1.0f / (sqrtf(c) + 1e-8f);
            }
        }
    }
    if (b == nbuckets - 1 && tid == 255) row_ptr[ntot] = bend;
    __syncthreads();
    for (int j = bstart + tid; j < bend; j += 256) {
        unsigned p = tmp[j];
        int local = p >> 17;
        int c = (int)(p & 0x1FFFFu);
        int pos = atomicAdd(&cur[local], 1);
        scols[pos] = c;
    }
}

// =================== feature kernels (unchanged from round 6) ===================

// xs[0:na+nb) = scales ⊙ concat(a,b);  acc_a = a; acc_b = b
__global__ void init_concat_kernel(const float* __restrict__ a, const float* __restrict__ b,
                                   int na, int nb, const float* __restrict__ scales,
                                   float* __restrict__ xs,
                                   float* __restrict__ acc_a, float* __restrict__ acc_b) {
    long long idx = (long long)blockIdx.x * blockDim.x + threadIdx.x;
    long long total = (long long)(na + nb) * FD;
    if (idx >= total) return;
    int row = (int)(idx >> 6);
    float v;
    if (row < na) {
        v = a[idx];
        acc_a[idx] = v;
    } else {
        long long j = idx - (long long)na * FD;
        v = b[j];
        acc_b[j] = v;
    }
    xs[idx] = scales[row] * v;
}

// one wave per row; edge loop software-pipelined (EDGE_CHUNK gathers in flight)
__device__ __forceinline__ float csr_row_gather(const int* __restrict__ row_ptr,
                                                const int* __restrict__ scols,
                                                const float* __restrict__ x,
                                                int wave, int lane) {
    int s = row_ptr[wave], e = row_ptr[wave + 1];
    float acc = 0.f;
    for (int base = s; base < e; base += EDGE_CHUNK) {
        int cbuf[EDGE_CHUNK];
#pragma unroll
        for (int k = 0; k < EDGE_CHUNK; ++k)
            cbuf[k] = scols[min(base + k, e - 1)];  // clamp tail (row non-empty here)
#pragma unroll
        for (int k = 0; k < EDGE_CHUNK; ++k) {
            float xv = x[(size_t)cbuf[k] * FD + lane];
            if (base + k < e) acc += xv;            // wave-uniform predicate
        }
    }
    return acc;
}

// f = scale * inv[row] * Σ xs[col];  if(write_xs) xs_out[row] = inv[row]*f;
// acc[row] += f / max(||f||, 1e-12)   (acc split across acc_a / acc_b at `split`)
__global__ void spmm_norm_kernel(const int* __restrict__ row_ptr,
                                 const int* __restrict__ scols,
                                 const float* __restrict__ inv,
                                 const float* __restrict__ x, float* __restrict__ xs_out,
                                 float* __restrict__ acc_a, float* __restrict__ acc_b,
                                 int split, int n, float scale, int write_xs) {
    int wave = (int)(((long long)blockIdx.x * blockDim.x + threadIdx.x) >> 6);
    if (wave >= n) return;
    int lane = threadIdx.x & 63;
    float iv = inv[wave];
    float f = scale * iv * csr_row_gather(row_ptr, scols, x, wave, lane);
    if (write_xs) xs_out[(size_t)wave * FD + lane] = iv * f;
    float ss = f * f;
#pragma unroll
    for (int o = 32; o >= 1; o >>= 1) ss += __shfl_xor(ss, o);
    float nrm = fmaxf(sqrtf(ss), 1e-12f);
    float add = f / nrm;
    if (wave < split)
        acc_a[(size_t)wave * FD + lane] += add;
    else
        acc_b[(size_t)(wave - split) * FD + lane] += add;
}

// y[row] = rowscale[row] * Σ x[col]  (bi aggregation)
__global__ void spmm_scale_kernel(const int* __restrict__ row_ptr,
                                  const int* __restrict__ scols,
                                  const float* __restrict__ rowscale,
                                  const float* __restrict__ x, float* __restrict__ y, int n) {
    int wave = (int)(((long long)blockIdx.x * blockDim.x + threadIdx.x) >> 6);
    if (wave >= n) return;
    int lane = threadIdx.x & 63;
    float acc = csr_row_gather(row_ptr, scols, x, wave, lane);
    y[(size_t)wave * FD + lane] = rowscale[wave] * acc;
}

extern "C" void kernel_launch(void* const* d_in, const int* in_sizes, int n_in,
                              void* d_out, int out_size, void* d_ws, size_t ws_size,
                              hipStream_t stream) {
    const float* users   = (const float*)d_in[0];
    const float* items   = (const float*)d_in[1];
    const float* bundles = (const float*)d_in[2];
    const int*   il_rows = (const int*)d_in[3];
    const int*   il_cols = (const int*)d_in[4];
    const int*   bl_rows = (const int*)d_in[6];
    const int*   bl_cols = (const int*)d_in[7];
    const int*   bi_rows = (const int*)d_in[9];
    const int*   bi_cols = (const int*)d_in[10];

    const int U = in_sizes[0] / FD;   // 50000
    const int I = in_sizes[1] / FD;   // 40000
    const int B = in_sizes[2] / FD;   // 20000
    const int nnz_il = in_sizes[3];   // 1,000,000
    const int nnz_bl = in_sizes[6];   //   600,000
    const int nnz_bi = in_sizes[9];   //   500,000
    const int n1 = U + I;             // 90000
    const int n2 = U + B;             // 70000
    const int ntot = n1 + B + n2;     // 180000 (il | bi | bl node spaces)
    const int nnz_tot = nnz_il + nnz_bi + nnz_bl;  // 2,100,000
    const int base_bi = n1, base_bl = n1 + B;
    const int nbuckets = (int)cdiv_ll(ntot, BROWS);  // 176

    float* out = (float*)d_out;
    // output layout: [il_users (U) | bl_users (U) | il_bundles (B) | bl_bundles (B)] x 64
    float* il_users_acc   = out;
    float* bl_users_acc   = out + (size_t)U * FD;
    float* il_bundles_out = out + (size_t)2 * U * FD;
    float* bl_bundles_acc = out + ((size_t)2 * U + B) * FD;

    // workspace layout
    float* ping          = (float*)d_ws;                       // n1 x 64
    float* pong          = ping + (size_t)n1 * FD;             // n1 x 64
    float* items_acc     = pong + (size_t)n1 * FD;             // I x 64
    int*   row_ptr       = (int*)(items_acc + (size_t)I * FD); // ntot + 1
    float* scales        = (float*)(row_ptr + ntot + 1);       // ntot
    int*   bucket_count  = (int*)(scales + ntot);              // MAXB
    int*   bucket_base   = bucket_count + MAXB;                // MAXB + 1
    int*   bucket_cursor = bucket_base + MAXB + 1;             // MAXB
    int*   scols         = bucket_cursor + MAXB;               // nnz_tot
    unsigned int* tmp    = (unsigned int*)pong;                // overlay (dead until spmm#1)

    const dim3 blk(256);
    const int grid_n1 = (int)cdiv_ll((long long)n1 * FD, 256);
    const int grid_n2 = (int)cdiv_ll((long long)n2 * FD, 256);
    const float h = 0.5f, th = 1.0f / 3.0f;

    // ---------------- fused CSR build (radix partition) ----------------
    hipMemsetAsync(bucket_count, 0, MAXB * sizeof(int), stream);
    bucket_hist_kernel<<<1024, blk, 0, stream>>>(
        il_rows, nnz_il, bi_rows, nnz_bi, bl_rows, nnz_bl,
        base_bi, base_bl, nnz_tot, nbuckets, bucket_count);
    bucket_scan_kernel<<<1, MAXB, 0, stream>>>(bucket_count, bucket_base,
                                               bucket_cursor, nbuckets);
    partition_kernel<<<(int)cdiv_ll(nnz_tot, PART_EPB), PART_BLOCK, 0, stream>>>(
        il_rows, il_cols, nnz_il, bi_rows, bi_cols, nnz_bi, bl_rows, bl_cols, nnz_bl,
        base_bi, base_bl, nnz_tot, nbuckets, bucket_cursor, tmp);
    finalize_kernel<<<nbuckets, blk, 0, stream>>>(tmp, bucket_base, row_ptr, scales,
                                                  scols, n1, B, ntot, nbuckets);

    // ---------------- item-level propagation (users + items, il graph) ------------
    init_concat_kernel<<<grid_n1, blk, 0, stream>>>(users, items, U, I, scales,
                                                    ping, il_users_acc, items_acc);
    spmm_norm_kernel<<<grid_n1, blk, 0, stream>>>(row_ptr, scols, scales, ping, pong,
                                                  il_users_acc, items_acc, U, n1, h, 1);
    spmm_norm_kernel<<<grid_n1, blk, 0, stream>>>(row_ptr, scols, scales, pong, ping,
                                                  il_users_acc, items_acc, U, n1, th, 0);

    // bundle aggregation: il_bundles = rowscale_bi * (BI @ il_items_acc)
    spmm_scale_kernel<<<(int)cdiv_ll((long long)B * FD, 256), blk, 0, stream>>>(
        row_ptr + base_bi, scols, scales + base_bi, items_acc, il_bundles_out, B);

    // ---------------- bundle-level propagation (users + bundles, bl graph) --------
    init_concat_kernel<<<grid_n2, blk, 0, stream>>>(users, bundles, U, B, scales + base_bl,
                                                    ping, bl_users_acc, bl_bundles_acc);
    spmm_norm_kernel<<<grid_n2, blk, 0, stream>>>(row_ptr + base_bl, scols, scales + base_bl,
                                                  ping, pong,
                                                  bl_users_acc, bl_bundles_acc, U, n2, h, 1);
    spmm_norm_kernel<<<grid_n2, blk, 0, stream>>>(row_ptr + base_bl, scols, scales + base_bl,
                                                  pong, ping,
                                                  bl_users_acc, bl_bundles_acc, U, n2, th, 0);
}

// Round 9
// 434.896 us; speedup vs baseline: 1.5445x; 1.2516x over previous
//
#include <hip/hip_runtime.h>

#define FD 64          // feature dim
#define EDGE_CHUNK 16  // software-pipelined gathers per batch
#define MAXB 256       // max buckets (ntot/1024 = 176 here)
#define BROWS 1024     // rows per bucket
#define PART_BLOCK 256
#define PART_VPT 16
#define PART_EPB (PART_BLOCK * PART_VPT)  // 4096 edges per partition block

static inline long long cdiv_ll(long long a, long long b) { return (a + b - 1) / b; }

// bf16 <-> f32 (RNE), accumulation stays f32 everywhere
__device__ __forceinline__ float bf2f(unsigned short u) {
    return __uint_as_float(((unsigned int)u) << 16);
}
__device__ __forceinline__ unsigned short f2bf(float f) {
    unsigned int x = __float_as_uint(f);
    x += 0x7FFFu + ((x >> 16) & 1u);
    return (unsigned short)(x >> 16);
}

// =================== fused CSR build via radix partition ===================
// node-space layout: [il nodes (n1) | bi rows (B) | bl nodes (n2)], bucket = node>>10

__global__ void bucket_hist_kernel(const int* __restrict__ r0, int nnz0,
                                   const int* __restrict__ r1, int nnz1,
                                   const int* __restrict__ r2, int nnz2,
                                   int b1, int b2, int nnz_tot, int nbuckets,
                                   int* __restrict__ bucket_count) {
    __shared__ int h[MAXB];
    for (int i = threadIdx.x; i < MAXB; i += blockDim.x) h[i] = 0;
    __syncthreads();
    int stride = gridDim.x * blockDim.x;
    for (int t = blockIdx.x * blockDim.x + threadIdx.x; t < nnz_tot; t += stride) {
        int node;
        if (t < nnz0) node = r0[t];
        else if (t < nnz0 + nnz1) node = b1 + r1[t - nnz0];
        else node = b2 + r2[t - nnz0 - nnz1];
        atomicAdd(&h[node >> 10], 1);
    }
    __syncthreads();
    for (int i = threadIdx.x; i < nbuckets; i += blockDim.x)
        if (h[i]) atomicAdd(&bucket_count[i], h[i]);
}

__global__ void bucket_scan_kernel(const int* __restrict__ bucket_count,
                                   int* __restrict__ bucket_base,
                                   int* __restrict__ bucket_cursor, int nbuckets) {
    __shared__ int sh[MAXB];
    int tid = threadIdx.x;
    int v = (tid < nbuckets) ? bucket_count[tid] : 0;
    sh[tid] = v;
    __syncthreads();
    for (int o = 1; o < MAXB; o <<= 1) {
        int t = (tid >= o) ? sh[tid - o] : 0;
        __syncthreads();
        sh[tid] += t;
        __syncthreads();
    }
    int excl = sh[tid] - v;
    if (tid < nbuckets) { bucket_base[tid] = excl; bucket_cursor[tid] = excl; }
    if (tid == nbuckets - 1) bucket_base[nbuckets] = sh[tid];
}

__global__ void partition_kernel(const int* __restrict__ r0, const int* __restrict__ c0, int nnz0,
                                 const int* __restrict__ r1, const int* __restrict__ c1, int nnz1,
                                 const int* __restrict__ r2, const int* __restrict__ c2, int nnz2,
                                 int b1, int b2, int nnz_tot, int nbuckets,
                                 int* __restrict__ bucket_cursor, unsigned int* __restrict__ tmp) {
    __shared__ int h[MAXB];
    __shared__ int base[MAXB];
    for (int i = threadIdx.x; i < MAXB; i += PART_BLOCK) h[i] = 0;
    __syncthreads();
    int blk_start = blockIdx.x * PART_EPB;
    int node[PART_VPT];
    int col[PART_VPT];
#pragma unroll
    for (int k = 0; k < PART_VPT; ++k) {
        int t = blk_start + k * PART_BLOCK + threadIdx.x;  // coalesced
        int nd = -1, cc = 0;
        if (t < nnz0) { nd = r0[t]; cc = c0[t]; }
        else if (t < nnz0 + nnz1) { int e = t - nnz0; nd = b1 + r1[e]; cc = c1[e]; }
        else if (t < nnz_tot)     { int e = t - nnz0 - nnz1; nd = b2 + r2[e]; cc = c2[e]; }
        node[k] = nd; col[k] = cc;
        if (nd >= 0) atomicAdd(&h[nd >> 10], 1);
    }
    __syncthreads();
    for (int i = threadIdx.x; i < nbuckets; i += PART_BLOCK) {
        int c = h[i];
        base[i] = c ? atomicAdd(&bucket_cursor[i], c) : 0;
        h[i] = 0;  // reuse as local write offset
    }
    __syncthreads();
#pragma unroll
    for (int k = 0; k < PART_VPT; ++k) {
        int nd = node[k];
        if (nd < 0) continue;
        int bkt = nd >> 10;
        int off = atomicAdd(&h[bkt], 1);
        tmp[base[bkt] + off] = ((unsigned)(nd & (BROWS - 1)) << 17) | (unsigned)col[k];
    }
}

__global__ void finalize_kernel(const unsigned int* __restrict__ tmp,
                                const int* __restrict__ bucket_base,
                                int* __restrict__ row_ptr, float* __restrict__ scales,
                                int* __restrict__ scols,
                                int n1, int nbi, int ntot, int nbuckets) {
    __shared__ int cnt[BROWS];
    __shared__ int cur[BROWS];
    __shared__ int tsum[256];
    int b = blockIdx.x;
    int tid = threadIdx.x;
    int rstart = b << 10;
    int bstart = bucket_base[b], bend = bucket_base[b + 1];
    for (int i = tid; i < BROWS; i += 256) cnt[i] = 0;
    __syncthreads();
    for (int j = bstart + tid; j < bend; j += 256)
        atomicAdd(&cnt[tmp[j] >> 17], 1);
    __syncthreads();
    int s0 = cnt[tid * 4], s1 = cnt[tid * 4 + 1], s2 = cnt[tid * 4 + 2], s3 = cnt[tid * 4 + 3];
    int ts = s0 + s1 + s2 + s3;
    tsum[tid] = ts;
    __syncthreads();
    for (int o = 1; o < 256; o <<= 1) {
        int t = (tid >= o) ? tsum[tid - o] : 0;
        __syncthreads();
        tsum[tid] += t;
        __syncthreads();
    }
    int p0 = bstart + tsum[tid] - ts;
    int p1 = p0 + s0, p2 = p1 + s1, p3 = p2 + s2;
    {
        int i0 = tid * 4;
        int pos[4] = {p0, p1, p2, p3};
        int cc[4] = {s0, s1, s2, s3};
#pragma unroll
        for (int q = 0; q < 4; ++q) {
            int i = i0 + q, r = rstart + i;
            if (r < ntot) {
                row_ptr[r] = pos[q];
                cur[i] = pos[q];
                float c = (float)cc[q];
                scales[r] = (r >= n1 && r < n1 + nbi) ? 1.0f / (c + 1e-8f)
                                                      : 1.0f / (sqrtf(c) + 1e-8f);
            }
        }
    }
    if (b == nbuckets - 1 && tid == 255) row_ptr[ntot] = bend;
    __syncthreads();
    for (int j = bstart + tid; j < bend; j += 256) {
        unsigned p = tmp[j];
        int local = p >> 17;
        int c = (int)(p & 0x1FFFFu);
        int pos = atomicAdd(&cur[local], 1);
        scols[pos] = c;
    }
}

// =================== feature kernels (bf16 gathered operand) ===================

// xs[0:na+nb) = bf16(scales ⊙ concat(a,b));  acc_a = a; acc_b = b (f32)
__global__ void init_concat_kernel(const float* __restrict__ a, const float* __restrict__ b,
                                   int na, int nb, const float* __restrict__ scales,
                                   unsigned short* __restrict__ xs,
                                   float* __restrict__ acc_a, float* __restrict__ acc_b) {
    long long idx = (long long)blockIdx.x * blockDim.x + threadIdx.x;
    long long total = (long long)(na + nb) * FD;
    if (idx >= total) return;
    int row = (int)(idx >> 6);
    float v;
    if (row < na) {
        v = a[idx];
        acc_a[idx] = v;
    } else {
        long long j = idx - (long long)na * FD;
        v = b[j];
        acc_b[j] = v;
    }
    xs[idx] = f2bf(scales[row] * v);
}

// one wave per row; edge loop software-pipelined (EDGE_CHUNK gathers in flight)
__device__ __forceinline__ float csr_row_gather(const int* __restrict__ row_ptr,
                                                const int* __restrict__ scols,
                                                const unsigned short* __restrict__ x,
                                                int wave, int lane) {
    int s = row_ptr[wave], e = row_ptr[wave + 1];
    float acc = 0.f;
    for (int base = s; base < e; base += EDGE_CHUNK) {
        int cbuf[EDGE_CHUNK];
#pragma unroll
        for (int k = 0; k < EDGE_CHUNK; ++k)
            cbuf[k] = scols[min(base + k, e - 1)];  // clamp tail (row non-empty here)
#pragma unroll
        for (int k = 0; k < EDGE_CHUNK; ++k) {
            float xv = bf2f(x[(size_t)cbuf[k] * FD + lane]);
            if (base + k < e) acc += xv;            // wave-uniform predicate
        }
    }
    return acc;
}

// f = scale * inv[row] * Σ xs[col];  if(write_xs) xs_out[row] = bf16(inv[row]*f);
// acc[row] += f / max(||f||,1e-12); items side optionally mirrors acc into bf16 shadow
__global__ void spmm_norm_kernel(const int* __restrict__ row_ptr,
                                 const int* __restrict__ scols,
                                 const float* __restrict__ inv,
                                 const unsigned short* __restrict__ x,
                                 unsigned short* __restrict__ xs_out,
                                 float* __restrict__ acc_a, float* __restrict__ acc_b,
                                 unsigned short* __restrict__ shadow_b,
                                 int split, int n, float scale, int write_xs) {
    int wave = (int)(((long long)blockIdx.x * blockDim.x + threadIdx.x) >> 6);
    if (wave >= n) return;
    int lane = threadIdx.x & 63;
    float iv = inv[wave];
    float f = scale * iv * csr_row_gather(row_ptr, scols, x, wave, lane);
    if (write_xs) xs_out[(size_t)wave * FD + lane] = f2bf(iv * f);
    float ss = f * f;
#pragma unroll
    for (int o = 32; o >= 1; o >>= 1) ss += __shfl_xor(ss, o);
    float nrm = fmaxf(sqrtf(ss), 1e-12f);
    float add = f / nrm;
    if (wave < split) {
        acc_a[(size_t)wave * FD + lane] += add;
    } else {
        size_t o = (size_t)(wave - split) * FD + lane;
        float nv = acc_b[o] + add;
        acc_b[o] = nv;
        if (shadow_b) shadow_b[o] = f2bf(nv);
    }
}

// y[row] = rowscale[row] * Σ x[col]  (bi aggregation, bf16 gather)
__global__ void spmm_scale_kernel(const int* __restrict__ row_ptr,
                                  const int* __restrict__ scols,
                                  const float* __restrict__ rowscale,
                                  const unsigned short* __restrict__ x,
                                  float* __restrict__ y, int n) {
    int wave = (int)(((long long)blockIdx.x * blockDim.x + threadIdx.x) >> 6);
    if (wave >= n) return;
    int lane = threadIdx.x & 63;
    float acc = csr_row_gather(row_ptr, scols, x, wave, lane);
    y[(size_t)wave * FD + lane] = rowscale[wave] * acc;
}

extern "C" void kernel_launch(void* const* d_in, const int* in_sizes, int n_in,
                              void* d_out, int out_size, void* d_ws, size_t ws_size,
                              hipStream_t stream) {
    const float* users   = (const float*)d_in[0];
    const float* items   = (const float*)d_in[1];
    const float* bundles = (const float*)d_in[2];
    const int*   il_rows = (const int*)d_in[3];
    const int*   il_cols = (const int*)d_in[4];
    const int*   bl_rows = (const int*)d_in[6];
    const int*   bl_cols = (const int*)d_in[7];
    const int*   bi_rows = (const int*)d_in[9];
    const int*   bi_cols = (const int*)d_in[10];

    const int U = in_sizes[0] / FD;   // 50000
    const int I = in_sizes[1] / FD;   // 40000
    const int B = in_sizes[2] / FD;   // 20000
    const int nnz_il = in_sizes[3];   // 1,000,000
    const int nnz_bl = in_sizes[6];   //   600,000
    const int nnz_bi = in_sizes[9];   //   500,000
    const int n1 = U + I;             // 90000
    const int n2 = U + B;             // 70000
    const int ntot = n1 + B + n2;     // 180000 (il | bi | bl node spaces)
    const int nnz_tot = nnz_il + nnz_bi + nnz_bl;  // 2,100,000
    const int base_bi = n1, base_bl = n1 + B;
    const int nbuckets = (int)cdiv_ll(ntot, BROWS);  // 176

    float* out = (float*)d_out;
    // output layout: [il_users (U) | bl_users (U) | il_bundles (B) | bl_bundles (B)] x 64
    float* il_users_acc   = out;
    float* bl_users_acc   = out + (size_t)U * FD;
    float* il_bundles_out = out + (size_t)2 * U * FD;
    float* bl_bundles_acc = out + ((size_t)2 * U + B) * FD;

    // workspace layout (bf16 ping/pong + items shadow, then CSR arrays)
    unsigned short* ping        = (unsigned short*)d_ws;        // n1 x 64 bf16
    unsigned short* pong        = ping + (size_t)n1 * FD;       // n1 x 64 bf16
    unsigned short* items_shad  = pong + (size_t)n1 * FD;       // I x 64 bf16
    float* items_acc    = (float*)(items_shad + (size_t)I * FD);   // I x 64 f32
    int*   row_ptr      = (int*)(items_acc + (size_t)I * FD);      // ntot + 1
    float* scales       = (float*)(row_ptr + ntot + 1);            // ntot
    int*   bucket_count = (int*)(scales + ntot);                   // MAXB
    int*   bucket_base  = bucket_count + MAXB;                     // MAXB + 1
    int*   bucket_cursor= bucket_base + MAXB + 1;                  // MAXB
    int*   scols        = bucket_cursor + MAXB;                    // nnz_tot
    unsigned int* tmp   = (unsigned int*)ping;  // overlay (ping+pong = 23MB >= 8.4MB;
                                                // dead until init_concat which runs after)

    const dim3 blk(256);
    const int grid_n1 = (int)cdiv_ll((long long)n1 * FD, 256);
    const int grid_n2 = (int)cdiv_ll((long long)n2 * FD, 256);
    const float h = 0.5f, th = 1.0f / 3.0f;

    // ---------------- fused CSR build (radix partition) ----------------
    hipMemsetAsync(bucket_count, 0, MAXB * sizeof(int), stream);
    bucket_hist_kernel<<<1024, blk, 0, stream>>>(
        il_rows, nnz_il, bi_rows, nnz_bi, bl_rows, nnz_bl,
        base_bi, base_bl, nnz_tot, nbuckets, bucket_count);
    bucket_scan_kernel<<<1, MAXB, 0, stream>>>(bucket_count, bucket_base,
                                               bucket_cursor, nbuckets);
    partition_kernel<<<(int)cdiv_ll(nnz_tot, PART_EPB), PART_BLOCK, 0, stream>>>(
        il_rows, il_cols, nnz_il, bi_rows, bi_cols, nnz_bi, bl_rows, bl_cols, nnz_bl,
        base_bi, base_bl, nnz_tot, nbuckets, bucket_cursor, tmp);
    finalize_kernel<<<nbuckets, blk, 0, stream>>>(tmp, bucket_base, row_ptr, scales,
                                                  scols, n1, B, ntot, nbuckets);

    // ---------------- item-level propagation (users + items, il graph) ------------
    init_concat_kernel<<<grid_n1, blk, 0, stream>>>(users, items, U, I, scales,
                                                    ping, il_users_acc, items_acc);
    spmm_norm_kernel<<<grid_n1, blk, 0, stream>>>(row_ptr, scols, scales, ping, pong,
                                                  il_users_acc, items_acc, (unsigned short*)0,
                                                  U, n1, h, 1);
    spmm_norm_kernel<<<grid_n1, blk, 0, stream>>>(row_ptr, scols, scales, pong, ping,
                                                  il_users_acc, items_acc, items_shad,
                                                  U, n1, th, 0);

    // bundle aggregation: il_bundles = rowscale_bi * (BI @ il_items_acc)  [bf16 gather]
    spmm_scale_kernel<<<(int)cdiv_ll((long long)B * FD, 256), blk, 0, stream>>>(
        row_ptr + base_bi, scols, scales + base_bi, items_shad, il_bundles_out, B);

    // ---------------- bundle-level propagation (users + bundles, bl graph) --------
    init_concat_kernel<<<grid_n2, blk, 0, stream>>>(users, bundles, U, B, scales + base_bl,
                                                    ping, bl_users_acc, bl_bundles_acc);
    spmm_norm_kernel<<<grid_n2, blk, 0, stream>>>(row_ptr + base_bl, scols, scales + base_bl,
                                                  ping, pong,
                                                  bl_users_acc, bl_bundles_acc, (unsigned short*)0,
                                                  U, n2, h, 1);
    spmm_norm_kernel<<<grid_n2, blk, 0, stream>>>(row_ptr + base_bl, scols, scales + base_bl,
                                                  pong, ping,
                                                  bl_users_acc, bl_bundles_acc, (unsigned short*)0,
                                                  U, n2, th, 0);
}

// Round 10
// 401.642 us; speedup vs baseline: 1.6724x; 1.0828x over previous
//
#include <hip/hip_runtime.h>

#define FD 64          // feature dim
#define EDGE_CHUNK 16  // software-pipelined gathers per batch
#define MAXB 256       // max buckets (ntot/1024 = 176 here)
#define BROWS 1024     // rows per bucket
#define FIN_BLOCK 1024 // finalize threads (= BROWS, one row per thread)
#define PART_BLOCK 256
#define PART_VPT 16
#define PART_EPB (PART_BLOCK * PART_VPT)  // 4096 edges per partition block

static inline long long cdiv_ll(long long a, long long b) { return (a + b - 1) / b; }

// bf16 <-> f32 (RNE), accumulation stays f32 everywhere
__device__ __forceinline__ float bf2f(unsigned short u) {
    return __uint_as_float(((unsigned int)u) << 16);
}
__device__ __forceinline__ unsigned short f2bf(float f) {
    unsigned int x = __float_as_uint(f);
    x += 0x7FFFu + ((x >> 16) & 1u);
    return (unsigned short)(x >> 16);
}

// =================== fused CSR build via radix partition ===================
// node-space layout: [il nodes (n1) | bi rows (B) | bl nodes (n2)], bucket = node>>10

__global__ void bucket_hist_kernel(const int* __restrict__ r0, int nnz0,
                                   const int* __restrict__ r1, int nnz1,
                                   const int* __restrict__ r2, int nnz2,
                                   int b1, int b2, int nnz_tot, int nbuckets,
                                   int* __restrict__ bucket_count) {
    __shared__ int h[MAXB];
    for (int i = threadIdx.x; i < MAXB; i += blockDim.x) h[i] = 0;
    __syncthreads();
    int stride = gridDim.x * blockDim.x;
    for (int t = blockIdx.x * blockDim.x + threadIdx.x; t < nnz_tot; t += stride) {
        int node;
        if (t < nnz0) node = r0[t];
        else if (t < nnz0 + nnz1) node = b1 + r1[t - nnz0];
        else node = b2 + r2[t - nnz0 - nnz1];
        atomicAdd(&h[node >> 10], 1);
    }
    __syncthreads();
    for (int i = threadIdx.x; i < nbuckets; i += blockDim.x)
        if (h[i]) atomicAdd(&bucket_count[i], h[i]);
}

__global__ void bucket_scan_kernel(const int* __restrict__ bucket_count,
                                   int* __restrict__ bucket_base,
                                   int* __restrict__ bucket_cursor, int nbuckets) {
    __shared__ int sh[MAXB];
    int tid = threadIdx.x;
    int v = (tid < nbuckets) ? bucket_count[tid] : 0;
    sh[tid] = v;
    __syncthreads();
    for (int o = 1; o < MAXB; o <<= 1) {
        int t = (tid >= o) ? sh[tid - o] : 0;
        __syncthreads();
        sh[tid] += t;
        __syncthreads();
    }
    int excl = sh[tid] - v;
    if (tid < nbuckets) { bucket_base[tid] = excl; bucket_cursor[tid] = excl; }
    if (tid == nbuckets - 1) bucket_base[nbuckets] = sh[tid];
}

__global__ void partition_kernel(const int* __restrict__ r0, const int* __restrict__ c0, int nnz0,
                                 const int* __restrict__ r1, const int* __restrict__ c1, int nnz1,
                                 const int* __restrict__ r2, const int* __restrict__ c2, int nnz2,
                                 int b1, int b2, int nnz_tot, int nbuckets,
                                 int* __restrict__ bucket_cursor, unsigned int* __restrict__ tmp) {
    __shared__ int h[MAXB];
    __shared__ int base[MAXB];
    for (int i = threadIdx.x; i < MAXB; i += PART_BLOCK) h[i] = 0;
    __syncthreads();
    int blk_start = blockIdx.x * PART_EPB;
    int node[PART_VPT];
    int col[PART_VPT];
#pragma unroll
    for (int k = 0; k < PART_VPT; ++k) {
        int t = blk_start + k * PART_BLOCK + threadIdx.x;  // coalesced
        int nd = -1, cc = 0;
        if (t < nnz0) { nd = r0[t]; cc = c0[t]; }
        else if (t < nnz0 + nnz1) { int e = t - nnz0; nd = b1 + r1[e]; cc = c1[e]; }
        else if (t < nnz_tot)     { int e = t - nnz0 - nnz1; nd = b2 + r2[e]; cc = c2[e]; }
        node[k] = nd; col[k] = cc;
        if (nd >= 0) atomicAdd(&h[nd >> 10], 1);
    }
    __syncthreads();
    for (int i = threadIdx.x; i < nbuckets; i += PART_BLOCK) {
        int c = h[i];
        base[i] = c ? atomicAdd(&bucket_cursor[i], c) : 0;
        h[i] = 0;  // reuse as local write offset
    }
    __syncthreads();
#pragma unroll
    for (int k = 0; k < PART_VPT; ++k) {
        int nd = node[k];
        if (nd < 0) continue;
        int bkt = nd >> 10;
        int off = atomicAdd(&h[bkt], 1);
        tmp[base[bkt] + off] = ((unsigned)(nd & (BROWS - 1)) << 17) | (unsigned)col[k];
    }
}

// one block of 1024 threads per bucket: one row per thread.
// count pass -> 1024-wide scan -> row_ptr/scales/cursors -> local scatter.
__global__ __launch_bounds__(FIN_BLOCK)
void finalize_kernel(const unsigned int* __restrict__ tmp,
                     const int* __restrict__ bucket_base,
                     int* __restrict__ row_ptr, float* __restrict__ scales,
                     int* __restrict__ scols,
                     int n1, int nbi, int ntot, int nbuckets) {
    __shared__ int cnt[BROWS];
    __shared__ int sc[BROWS];
    __shared__ int cur[BROWS];
    int b = blockIdx.x;
    int tid = threadIdx.x;
    int rstart = b << 10;
    int bstart = bucket_base[b], bend = bucket_base[b + 1];
    cnt[tid] = 0;
    __syncthreads();
    for (int j = bstart + tid; j < bend; j += FIN_BLOCK)
        atomicAdd(&cnt[tmp[j] >> 17], 1);
    __syncthreads();
    int v = cnt[tid];
    sc[tid] = v;
    __syncthreads();
    for (int o = 1; o < FIN_BLOCK; o <<= 1) {
        int t = (tid >= o) ? sc[tid - o] : 0;
        __syncthreads();
        sc[tid] += t;
        __syncthreads();
    }
    int p = bstart + sc[tid] - v;  // exclusive prefix -> absolute position
    int r = rstart + tid;
    if (r < ntot) {
        row_ptr[r] = p;
        cur[tid] = p;
        float c = (float)v;
        scales[r] = (r >= n1 && r < n1 + nbi) ? 1.0f / (c + 1e-8f)
                                              : 1.0f / (sqrtf(c) + 1e-8f);
    }
    if (b == nbuckets - 1 && tid == FIN_BLOCK - 1) row_ptr[ntot] = bend;
    __syncthreads();
    for (int j = bstart + tid; j < bend; j += FIN_BLOCK) {
        unsigned pk = tmp[j];
        int pos = atomicAdd(&cur[pk >> 17], 1);
        scols[pos] = (int)(pk & 0x1FFFFu);
    }
}

// =================== feature kernels (bf16 gathered operand) ===================

// xs[0:na+nb) = bf16(scales ⊙ concat(a,b));  acc_a = a; acc_b = b (f32)
__global__ void init_concat_kernel(const float* __restrict__ a, const float* __restrict__ b,
                                   int na, int nb, const float* __restrict__ scales,
                                   unsigned short* __restrict__ xs,
                                   float* __restrict__ acc_a, float* __restrict__ acc_b) {
    long long idx = (long long)blockIdx.x * blockDim.x + threadIdx.x;
    long long total = (long long)(na + nb) * FD;
    if (idx >= total) return;
    int row = (int)(idx >> 6);
    float v;
    if (row < na) {
        v = a[idx];
        acc_a[idx] = v;
    } else {
        long long j = idx - (long long)na * FD;
        v = b[j];
        acc_b[j] = v;
    }
    xs[idx] = f2bf(scales[row] * v);
}

// one wave per row; edge loop software-pipelined (EDGE_CHUNK gathers in flight)
__device__ __forceinline__ float csr_row_gather(const int* __restrict__ row_ptr,
                                                const int* __restrict__ scols,
                                                const unsigned short* __restrict__ x,
                                                int wave, int lane) {
    int s = row_ptr[wave], e = row_ptr[wave + 1];
    float acc = 0.f;
    for (int base = s; base < e; base += EDGE_CHUNK) {
        int cbuf[EDGE_CHUNK];
#pragma unroll
        for (int k = 0; k < EDGE_CHUNK; ++k)
            cbuf[k] = scols[min(base + k, e - 1)];  // clamp tail (row non-empty here)
#pragma unroll
        for (int k = 0; k < EDGE_CHUNK; ++k) {
            float xv = bf2f(x[(size_t)cbuf[k] * FD + lane]);
            if (base + k < e) acc += xv;            // wave-uniform predicate
        }
    }
    return acc;
}

// f = scale * inv[row] * Σ xs[col];  if(write_xs) xs_out[row] = bf16(inv[row]*f);
// acc[row] += f / max(||f||,1e-12); items side optionally mirrors acc into bf16 shadow
__global__ void spmm_norm_kernel(const int* __restrict__ row_ptr,
                                 const int* __restrict__ scols,
                                 const float* __restrict__ inv,
                                 const unsigned short* __restrict__ x,
                                 unsigned short* __restrict__ xs_out,
                                 float* __restrict__ acc_a, float* __restrict__ acc_b,
                                 unsigned short* __restrict__ shadow_b,
                                 int split, int n, float scale, int write_xs) {
    int wave = (int)(((long long)blockIdx.x * blockDim.x + threadIdx.x) >> 6);
    if (wave >= n) return;
    int lane = threadIdx.x & 63;
    float iv = inv[wave];
    float f = scale * iv * csr_row_gather(row_ptr, scols, x, wave, lane);
    if (write_xs) xs_out[(size_t)wave * FD + lane] = f2bf(iv * f);
    float ss = f * f;
#pragma unroll
    for (int o = 32; o >= 1; o >>= 1) ss += __shfl_xor(ss, o);
    float nrm = fmaxf(sqrtf(ss), 1e-12f);
    float add = f / nrm;
    if (wave < split) {
        acc_a[(size_t)wave * FD + lane] += add;
    } else {
        size_t o = (size_t)(wave - split) * FD + lane;
        float nv = acc_b[o] + add;
        acc_b[o] = nv;
        if (shadow_b) shadow_b[o] = f2bf(nv);
    }
}

// y[row] = rowscale[row] * Σ x[col]  (bi aggregation, bf16 gather)
__global__ void spmm_scale_kernel(const int* __restrict__ row_ptr,
                                  const int* __restrict__ scols,
                                  const float* __restrict__ rowscale,
                                  const unsigned short* __restrict__ x,
                                  float* __restrict__ y, int n) {
    int wave = (int)(((long long)blockIdx.x * blockDim.x + threadIdx.x) >> 6);
    if (wave >= n) return;
    int lane = threadIdx.x & 63;
    float acc = csr_row_gather(row_ptr, scols, x, wave, lane);
    y[(size_t)wave * FD + lane] = rowscale[wave] * acc;
}

extern "C" void kernel_launch(void* const* d_in, const int* in_sizes, int n_in,
                              void* d_out, int out_size, void* d_ws, size_t ws_size,
                              hipStream_t stream) {
    const float* users   = (const float*)d_in[0];
    const float* items   = (const float*)d_in[1];
    const float* bundles = (const float*)d_in[2];
    const int*   il_rows = (const int*)d_in[3];
    const int*   il_cols = (const int*)d_in[4];
    const int*   bl_rows = (const int*)d_in[6];
    const int*   bl_cols = (const int*)d_in[7];
    const int*   bi_rows = (const int*)d_in[9];
    const int*   bi_cols = (const int*)d_in[10];

    const int U = in_sizes[0] / FD;   // 50000
    const int I = in_sizes[1] / FD;   // 40000
    const int B = in_sizes[2] / FD;   // 20000
    const int nnz_il = in_sizes[3];   // 1,000,000
    const int nnz_bl = in_sizes[6];   //   600,000
    const int nnz_bi = in_sizes[9];   //   500,000
    const int n1 = U + I;             // 90000
    const int n2 = U + B;             // 70000
    const int ntot = n1 + B + n2;     // 180000 (il | bi | bl node spaces)
    const int nnz_tot = nnz_il + nnz_bi + nnz_bl;  // 2,100,000
    const int base_bi = n1, base_bl = n1 + B;
    const int nbuckets = (int)cdiv_ll(ntot, BROWS);  // 176

    float* out = (float*)d_out;
    // output layout: [il_users (U) | bl_users (U) | il_bundles (B) | bl_bundles (B)] x 64
    float* il_users_acc   = out;
    float* bl_users_acc   = out + (size_t)U * FD;
    float* il_bundles_out = out + (size_t)2 * U * FD;
    float* bl_bundles_acc = out + ((size_t)2 * U + B) * FD;

    // workspace layout (bf16 ping/pong + items shadow, then CSR arrays)
    unsigned short* ping        = (unsigned short*)d_ws;        // n1 x 64 bf16
    unsigned short* pong        = ping + (size_t)n1 * FD;       // n1 x 64 bf16
    unsigned short* items_shad  = pong + (size_t)n1 * FD;       // I x 64 bf16
    float* items_acc    = (float*)(items_shad + (size_t)I * FD);   // I x 64 f32
    int*   row_ptr      = (int*)(items_acc + (size_t)I * FD);      // ntot + 1
    float* scales       = (float*)(row_ptr + ntot + 1);            // ntot
    int*   bucket_count = (int*)(scales + ntot);                   // MAXB
    int*   bucket_base  = bucket_count + MAXB;                     // MAXB + 1
    int*   bucket_cursor= bucket_base + MAXB + 1;                  // MAXB
    int*   scols        = bucket_cursor + MAXB;                    // nnz_tot
    unsigned int* tmp   = (unsigned int*)ping;  // overlay (ping+pong = 23MB >= 8.4MB;
                                                // dead until init_concat which runs after)

    const dim3 blk(256);
    const int grid_n1 = (int)cdiv_ll((long long)n1 * FD, 256);
    const int grid_n2 = (int)cdiv_ll((long long)n2 * FD, 256);
    const float h = 0.5f, th = 1.0f / 3.0f;

    // ---------------- fused CSR build (radix partition) ----------------
    hipMemsetAsync(bucket_count, 0, MAXB * sizeof(int), stream);
    bucket_hist_kernel<<<1024, blk, 0, stream>>>(
        il_rows, nnz_il, bi_rows, nnz_bi, bl_rows, nnz_bl,
        base_bi, base_bl, nnz_tot, nbuckets, bucket_count);
    bucket_scan_kernel<<<1, MAXB, 0, stream>>>(bucket_count, bucket_base,
                                               bucket_cursor, nbuckets);
    partition_kernel<<<(int)cdiv_ll(nnz_tot, PART_EPB), PART_BLOCK, 0, stream>>>(
        il_rows, il_cols, nnz_il, bi_rows, bi_cols, nnz_bi, bl_rows, bl_cols, nnz_bl,
        base_bi, base_bl, nnz_tot, nbuckets, bucket_cursor, tmp);
    finalize_kernel<<<nbuckets, FIN_BLOCK, 0, stream>>>(tmp, bucket_base, row_ptr, scales,
                                                        scols, n1, B, ntot, nbuckets);

    // ---------------- item-level propagation (users + items, il graph) ------------
    init_concat_kernel<<<grid_n1, blk, 0, stream>>>(users, items, U, I, scales,
                                                    ping, il_users_acc, items_acc);
    spmm_norm_kernel<<<grid_n1, blk, 0, stream>>>(row_ptr, scols, scales, ping, pong,
                                                  il_users_acc, items_acc, (unsigned short*)0,
                                                  U, n1, h, 1);
    spmm_norm_kernel<<<grid_n1, blk, 0, stream>>>(row_ptr, scols, scales, pong, ping,
                                                  il_users_acc, items_acc, items_shad,
                                                  U, n1, th, 0);

    // bundle aggregation: il_bundles = rowscale_bi * (BI @ il_items_acc)  [bf16 gather]
    spmm_scale_kernel<<<(int)cdiv_ll((long long)B * FD, 256), blk, 0, stream>>>(
        row_ptr + base_bi, scols, scales + base_bi, items_shad, il_bundles_out, B);

    // ---------------- bundle-level propagation (users + bundles, bl graph) --------
    init_concat_kernel<<<grid_n2, blk, 0, stream>>>(users, bundles, U, B, scales + base_bl,
                                                    ping, bl_users_acc, bl_bundles_acc);
    spmm_norm_kernel<<<grid_n2, blk, 0, stream>>>(row_ptr + base_bl, scols, scales + base_bl,
                                                  ping, pong,
                                                  bl_users_acc, bl_bundles_acc, (unsigned short*)0,
                                                  U, n2, h, 1);
    spmm_norm_kernel<<<grid_n2, blk, 0, stream>>>(row_ptr + base_bl, scols, scales + base_bl,
                                                  pong, ping,
                                                  bl_users_acc, bl_bundles_acc, (unsigned short*)0,
                                                  U, n2, th, 0);
}

// Round 11
// 377.974 us; speedup vs baseline: 1.7771x; 1.0626x over previous
//
#include <hip/hip_runtime.h>

#define FD 64          // feature dim
#define EDGE_CHUNK 16  // edges per software-pipelined batch (8 pair-gathers in flight)
#define MAXB 256       // max buckets (ntot/1024 = 176 here)
#define BROWS 1024     // rows per bucket
#define FIN_BLOCK 1024 // finalize threads (= BROWS, one row per thread)
#define PART_BLOCK 256
#define PART_VPT 16
#define PART_EPB (PART_BLOCK * PART_VPT)  // 4096 edges per partition block

static inline long long cdiv_ll(long long a, long long b) { return (a + b - 1) / b; }

// bf16 <-> f32 (RNE), accumulation stays f32 everywhere
__device__ __forceinline__ float bf2f(unsigned short u) {
    return __uint_as_float(((unsigned int)u) << 16);
}
__device__ __forceinline__ unsigned short f2bf(float f) {
    unsigned int x = __float_as_uint(f);
    x += 0x7FFFu + ((x >> 16) & 1u);
    return (unsigned short)(x >> 16);
}

// =================== fused CSR build via radix partition ===================
// node-space layout: [il nodes (n1) | bi rows (B) | bl nodes (n2)], bucket = node>>10

__global__ void bucket_hist_kernel(const int* __restrict__ r0, int nnz0,
                                   const int* __restrict__ r1, int nnz1,
                                   const int* __restrict__ r2, int nnz2,
                                   int b1, int b2, int nnz_tot, int nbuckets,
                                   int* __restrict__ bucket_count) {
    __shared__ int h[MAXB];
    for (int i = threadIdx.x; i < MAXB; i += blockDim.x) h[i] = 0;
    __syncthreads();
    int stride = gridDim.x * blockDim.x;
    for (int t = blockIdx.x * blockDim.x + threadIdx.x; t < nnz_tot; t += stride) {
        int node;
        if (t < nnz0) node = r0[t];
        else if (t < nnz0 + nnz1) node = b1 + r1[t - nnz0];
        else node = b2 + r2[t - nnz0 - nnz1];
        atomicAdd(&h[node >> 10], 1);
    }
    __syncthreads();
    for (int i = threadIdx.x; i < nbuckets; i += blockDim.x)
        if (h[i]) atomicAdd(&bucket_count[i], h[i]);
}

__global__ void bucket_scan_kernel(const int* __restrict__ bucket_count,
                                   int* __restrict__ bucket_base,
                                   int* __restrict__ bucket_cursor, int nbuckets) {
    __shared__ int sh[MAXB];
    int tid = threadIdx.x;
    int v = (tid < nbuckets) ? bucket_count[tid] : 0;
    sh[tid] = v;
    __syncthreads();
    for (int o = 1; o < MAXB; o <<= 1) {
        int t = (tid >= o) ? sh[tid - o] : 0;
        __syncthreads();
        sh[tid] += t;
        __syncthreads();
    }
    int excl = sh[tid] - v;
    if (tid < nbuckets) { bucket_base[tid] = excl; bucket_cursor[tid] = excl; }
    if (tid == nbuckets - 1) bucket_base[nbuckets] = sh[tid];
}

__global__ void partition_kernel(const int* __restrict__ r0, const int* __restrict__ c0, int nnz0,
                                 const int* __restrict__ r1, const int* __restrict__ c1, int nnz1,
                                 const int* __restrict__ r2, const int* __restrict__ c2, int nnz2,
                                 int b1, int b2, int nnz_tot, int nbuckets,
                                 int* __restrict__ bucket_cursor, unsigned int* __restrict__ tmp) {
    __shared__ int h[MAXB];
    __shared__ int base[MAXB];
    for (int i = threadIdx.x; i < MAXB; i += PART_BLOCK) h[i] = 0;
    __syncthreads();
    int blk_start = blockIdx.x * PART_EPB;
    int node[PART_VPT];
    int col[PART_VPT];
#pragma unroll
    for (int k = 0; k < PART_VPT; ++k) {
        int t = blk_start + k * PART_BLOCK + threadIdx.x;  // coalesced
        int nd = -1, cc = 0;
        if (t < nnz0) { nd = r0[t]; cc = c0[t]; }
        else if (t < nnz0 + nnz1) { int e = t - nnz0; nd = b1 + r1[e]; cc = c1[e]; }
        else if (t < nnz_tot)     { int e = t - nnz0 - nnz1; nd = b2 + r2[e]; cc = c2[e]; }
        node[k] = nd; col[k] = cc;
        if (nd >= 0) atomicAdd(&h[nd >> 10], 1);
    }
    __syncthreads();
    for (int i = threadIdx.x; i < nbuckets; i += PART_BLOCK) {
        int c = h[i];
        base[i] = c ? atomicAdd(&bucket_cursor[i], c) : 0;
        h[i] = 0;  // reuse as local write offset
    }
    __syncthreads();
#pragma unroll
    for (int k = 0; k < PART_VPT; ++k) {
        int nd = node[k];
        if (nd < 0) continue;
        int bkt = nd >> 10;
        int off = atomicAdd(&h[bkt], 1);
        tmp[base[bkt] + off] = ((unsigned)(nd & (BROWS - 1)) << 17) | (unsigned)col[k];
    }
}

// one block of 1024 threads per bucket: one row per thread.
__global__ __launch_bounds__(FIN_BLOCK)
void finalize_kernel(const unsigned int* __restrict__ tmp,
                     const int* __restrict__ bucket_base,
                     int* __restrict__ row_ptr, float* __restrict__ scales,
                     int* __restrict__ scols,
                     int n1, int nbi, int ntot, int nbuckets) {
    __shared__ int cnt[BROWS];
    __shared__ int sc[BROWS];
    __shared__ int cur[BROWS];
    int b = blockIdx.x;
    int tid = threadIdx.x;
    int rstart = b << 10;
    int bstart = bucket_base[b], bend = bucket_base[b + 1];
    cnt[tid] = 0;
    __syncthreads();
    for (int j = bstart + tid; j < bend; j += FIN_BLOCK)
        atomicAdd(&cnt[tmp[j] >> 17], 1);
    __syncthreads();
    int v = cnt[tid];
    sc[tid] = v;
    __syncthreads();
    for (int o = 1; o < FIN_BLOCK; o <<= 1) {
        int t = (tid >= o) ? sc[tid - o] : 0;
        __syncthreads();
        sc[tid] += t;
        __syncthreads();
    }
    int p = bstart + sc[tid] - v;  // exclusive prefix -> absolute position
    int r = rstart + tid;
    if (r < ntot) {
        row_ptr[r] = p;
        cur[tid] = p;
        float c = (float)v;
        scales[r] = (r >= n1 && r < n1 + nbi) ? 1.0f / (c + 1e-8f)
                                              : 1.0f / (sqrtf(c) + 1e-8f);
    }
    if (b == nbuckets - 1 && tid == FIN_BLOCK - 1) row_ptr[ntot] = bend;
    __syncthreads();
    for (int j = bstart + tid; j < bend; j += FIN_BLOCK) {
        unsigned pk = tmp[j];
        int pos = atomicAdd(&cur[pk >> 17], 1);
        scols[pos] = (int)(pk & 0x1FFFFu);
    }
}

// =================== feature kernels (bf16 paired-edge gather) ===================

// xs[0:na+nb) = bf16(scales ⊙ concat(a,b));  acc_a = a; acc_b = b (f32)
__global__ void init_concat_kernel(const float* __restrict__ a, const float* __restrict__ b,
                                   int na, int nb, const float* __restrict__ scales,
                                   unsigned short* __restrict__ xs,
                                   float* __restrict__ acc_a, float* __restrict__ acc_b) {
    long long idx = (long long)blockIdx.x * blockDim.x + threadIdx.x;
    long long total = (long long)(na + nb) * FD;
    if (idx >= total) return;
    int row = (int)(idx >> 6);
    float v;
    if (row < na) {
        v = a[idx];
        acc_a[idx] = v;
    } else {
        long long j = idx - (long long)na * FD;
        v = b[j];
        acc_b[j] = v;
    }
    xs[idx] = f2bf(scales[row] * v);
}

// paired-edge gather: lane = (half = l>>5, sub = l&31). Per edge pair, half h
// handles edge base+k+h; each lane loads uint = 2 bf16 dims at x[c][2*sub].
// Returns this lane's dim-pair (2*sub, 2*sub+1) row sum (both halves hold it).
__device__ __forceinline__ float2 csr_row_gather2(const int* __restrict__ row_ptr,
                                                  const int* __restrict__ scols,
                                                  const unsigned short* __restrict__ x,
                                                  int row, int sub, int half) {
    int s = row_ptr[row], e = row_ptr[row + 1];
    float ax = 0.f, ay = 0.f;
    const unsigned short* xb = x + 2 * sub;
    for (int base = s; base < e; base += EDGE_CHUNK) {
        int cbuf[EDGE_CHUNK];
#pragma unroll
        for (int k = 0; k < EDGE_CHUNK; ++k)
            cbuf[k] = scols[min(base + k, e - 1)];  // clamp tail (row non-empty here)
#pragma unroll
        for (int k = 0; k < EDGE_CHUNK; k += 2) {
            int c = half ? cbuf[k + 1] : cbuf[k];   // compile-time indices + cndmask
            unsigned int v = *reinterpret_cast<const unsigned int*>(xb + (size_t)c * FD);
            float lo = bf2f((unsigned short)(v & 0xFFFFu));
            float hi = bf2f((unsigned short)(v >> 16));
            if (base + k + half < e) { ax += lo; ay += hi; }  // per-half predicate
        }
    }
    ax += __shfl_xor(ax, 32);  // fold halves; both now hold the full pair sum
    ay += __shfl_xor(ay, 32);
    return make_float2(ax, ay);
}

// f = scale * inv[row] * Σ xs[col];  if(write_xs) xs_out[row] = bf16(inv[row]*f);
// acc[row] += f / max(||f||,1e-12); items side optionally mirrors acc into bf16 shadow
__global__ void spmm_norm_kernel(const int* __restrict__ row_ptr,
                                 const int* __restrict__ scols,
                                 const float* __restrict__ inv,
                                 const unsigned short* __restrict__ x,
                                 unsigned short* __restrict__ xs_out,
                                 float* __restrict__ acc_a, float* __restrict__ acc_b,
                                 unsigned short* __restrict__ shadow_b,
                                 int split, int n, float scale, int write_xs) {
    int wave = (int)(((long long)blockIdx.x * blockDim.x + threadIdx.x) >> 6);
    if (wave >= n) return;
    int lane = threadIdx.x & 63;
    int sub = lane & 31, half = lane >> 5;
    float iv = inv[wave];
    float2 g = csr_row_gather2(row_ptr, scols, x, wave, sub, half);
    float fx = scale * iv * g.x, fy = scale * iv * g.y;
    float ss = fx * fx + fy * fy;
#pragma unroll
    for (int o = 16; o >= 1; o >>= 1) ss += __shfl_xor(ss, o);  // stays within half
    float nrm = fmaxf(sqrtf(ss), 1e-12f);
    float addx = fx / nrm, addy = fy / nrm;
    if (half == 0) {
        size_t off = (size_t)wave * FD + 2 * sub;
        if (write_xs) {
            unsigned int pk = ((unsigned int)f2bf(iv * fy) << 16) | f2bf(iv * fx);
            *reinterpret_cast<unsigned int*>(xs_out + off) = pk;
        }
        if (wave < split) {
            float2* p = reinterpret_cast<float2*>(acc_a + off);
            float2 v = *p;
            v.x += addx; v.y += addy;
            *p = v;
        } else {
            size_t o2 = (size_t)(wave - split) * FD + 2 * sub;
            float2* p = reinterpret_cast<float2*>(acc_b + o2);
            float2 v = *p;
            v.x += addx; v.y += addy;
            *p = v;
            if (shadow_b) {
                unsigned int sp = ((unsigned int)f2bf(v.y) << 16) | f2bf(v.x);
                *reinterpret_cast<unsigned int*>(shadow_b + o2) = sp;
            }
        }
    }
}

// y[row] = rowscale[row] * Σ x[col]  (bi aggregation, paired bf16 gather)
__global__ void spmm_scale_kernel(const int* __restrict__ row_ptr,
                                  const int* __restrict__ scols,
                                  const float* __restrict__ rowscale,
                                  const unsigned short* __restrict__ x,
                                  float* __restrict__ y, int n) {
    int wave = (int)(((long long)blockIdx.x * blockDim.x + threadIdx.x) >> 6);
    if (wave >= n) return;
    int lane = threadIdx.x & 63;
    int sub = lane & 31, half = lane >> 5;
    float2 g = csr_row_gather2(row_ptr, scols, x, wave, sub, half);
    if (half == 0) {
        float rs = rowscale[wave];
        float2* p = reinterpret_cast<float2*>(y + (size_t)wave * FD + 2 * sub);
        *p = make_float2(rs * g.x, rs * g.y);
    }
}

extern "C" void kernel_launch(void* const* d_in, const int* in_sizes, int n_in,
                              void* d_out, int out_size, void* d_ws, size_t ws_size,
                              hipStream_t stream) {
    const float* users   = (const float*)d_in[0];
    const float* items   = (const float*)d_in[1];
    const float* bundles = (const float*)d_in[2];
    const int*   il_rows = (const int*)d_in[3];
    const int*   il_cols = (const int*)d_in[4];
    const int*   bl_rows = (const int*)d_in[6];
    const int*   bl_cols = (const int*)d_in[7];
    const int*   bi_rows = (const int*)d_in[9];
    const int*   bi_cols = (const int*)d_in[10];

    const int U = in_sizes[0] / FD;   // 50000
    const int I = in_sizes[1] / FD;   // 40000
    const int B = in_sizes[2] / FD;   // 20000
    const int nnz_il = in_sizes[3];   // 1,000,000
    const int nnz_bl = in_sizes[6];   //   600,000
    const int nnz_bi = in_sizes[9];   //   500,000
    const int n1 = U + I;             // 90000
    const int n2 = U + B;             // 70000
    const int ntot = n1 + B + n2;     // 180000 (il | bi | bl node spaces)
    const int nnz_tot = nnz_il + nnz_bi + nnz_bl;  // 2,100,000
    const int base_bi = n1, base_bl = n1 + B;
    const int nbuckets = (int)cdiv_ll(ntot, BROWS);  // 176

    float* out = (float*)d_out;
    // output layout: [il_users (U) | bl_users (U) | il_bundles (B) | bl_bundles (B)] x 64
    float* il_users_acc   = out;
    float* bl_users_acc   = out + (size_t)U * FD;
    float* il_bundles_out = out + (size_t)2 * U * FD;
    float* bl_bundles_acc = out + ((size_t)2 * U + B) * FD;

    // workspace layout (bf16 ping/pong + items shadow, then CSR arrays)
    unsigned short* ping        = (unsigned short*)d_ws;        // n1 x 64 bf16
    unsigned short* pong        = ping + (size_t)n1 * FD;       // n1 x 64 bf16
    unsigned short* items_shad  = pong + (size_t)n1 * FD;       // I x 64 bf16
    float* items_acc    = (float*)(items_shad + (size_t)I * FD);   // I x 64 f32
    int*   row_ptr      = (int*)(items_acc + (size_t)I * FD);      // ntot + 1
    float* scales       = (float*)(row_ptr + ntot + 1);            // ntot
    int*   bucket_count = (int*)(scales + ntot);                   // MAXB
    int*   bucket_base  = bucket_count + MAXB;                     // MAXB + 1
    int*   bucket_cursor= bucket_base + MAXB + 1;                  // MAXB
    int*   scols        = bucket_cursor + MAXB;                    // nnz_tot
    unsigned int* tmp   = (unsigned int*)ping;  // overlay (ping+pong = 23MB >= 8.4MB;
                                                // dead until init_concat which runs after)

    const dim3 blk(256);
    const int grid_n1 = (int)cdiv_ll((long long)n1 * FD, 256);
    const int grid_n2 = (int)cdiv_ll((long long)n2 * FD, 256);
    const float h = 0.5f, th = 1.0f / 3.0f;

    // ---------------- fused CSR build (radix partition) ----------------
    hipMemsetAsync(bucket_count, 0, MAXB * sizeof(int), stream);
    bucket_hist_kernel<<<1024, blk, 0, stream>>>(
        il_rows, nnz_il, bi_rows, nnz_bi, bl_rows, nnz_bl,
        base_bi, base_bl, nnz_tot, nbuckets, bucket_count);
    bucket_scan_kernel<<<1, MAXB, 0, stream>>>(bucket_count, bucket_base,
                                               bucket_cursor, nbuckets);
    partition_kernel<<<(int)cdiv_ll(nnz_tot, PART_EPB), PART_BLOCK, 0, stream>>>(
        il_rows, il_cols, nnz_il, bi_rows, bi_cols, nnz_bi, bl_rows, bl_cols, nnz_bl,
        base_bi, base_bl, nnz_tot, nbuckets, bucket_cursor, tmp);
    finalize_kernel<<<nbuckets, FIN_BLOCK, 0, stream>>>(tmp, bucket_base, row_ptr, scales,
                                                        scols, n1, B, ntot, nbuckets);

    // ---------------- item-level propagation (users + items, il graph) ------------
    init_concat_kernel<<<grid_n1, blk, 0, stream>>>(users, items, U, I, scales,
                                                    ping, il_users_acc, items_acc);
    spmm_norm_kernel<<<grid_n1, blk, 0, stream>>>(row_ptr, scols, scales, ping, pong,
                                                  il_users_acc, items_acc, (unsigned short*)0,
                                                  U, n1, h, 1);
    spmm_norm_kernel<<<grid_n1, blk, 0, stream>>>(row_ptr, scols, scales, pong, ping,
                                                  il_users_acc, items_acc, items_shad,
                                                  U, n1, th, 0);

    // bundle aggregation: il_bundles = rowscale_bi * (BI @ il_items_acc)  [bf16 gather]
    spmm_scale_kernel<<<(int)cdiv_ll((long long)B * FD, 256), blk, 0, stream>>>(
        row_ptr + base_bi, scols, scales + base_bi, items_shad, il_bundles_out, B);

    // ---------------- bundle-level propagation (users + bundles, bl graph) --------
    init_concat_kernel<<<grid_n2, blk, 0, stream>>>(users, bundles, U, B, scales + base_bl,
                                                    ping, bl_users_acc, bl_bundles_acc);
    spmm_norm_kernel<<<grid_n2, blk, 0, stream>>>(row_ptr + base_bl, scols, scales + base_bl,
                                                  ping, pong,
                                                  bl_users_acc, bl_bundles_acc, (unsigned short*)0,
                                                  U, n2, h, 1);
    spmm_norm_kernel<<<grid_n2, blk, 0, stream>>>(row_ptr + base_bl, scols, scales + base_bl,
                                                  pong, ping,
                                                  bl_users_acc, bl_bundles_acc, (unsigned short*)0,
                                                  U, n2, th, 0);
}